// Round 4
// baseline (696.804 us; speedup 1.0000x reference)
//
#include <hip/hip_runtime.h>
#include <math.h>

#define N_NODE 100000
#define N_EDGE 1600000
#define D_FEAT 64
#define DEPTH  3
#define OUT_STRIDE ((DEPTH + 1) * D_FEAT)   // 256 floats per node row

// ---- bucketed CSR build ----------------------------------------------------
#define NB  256                      // coarse buckets
#define RPB 391                      // rows per bucket: 256*391 = 100096 >= N
#define CAP 8192                     // per-bucket edge capacity (mean 6250, +24 sigma)
#define S1_BS 512
#define S1_CHUNK 8192                // edges per stage1 block
#define S1_BLOCKS ((N_EDGE + S1_CHUNK - 1) / S1_CHUNK)   // 196

// ---- feature-split spmm ----------------------------------------------------
#define PASSES 4
#define FPP    16                    // feats per pass; slice = N*FPP*2B = 3.2MB
#define NODES_PER_BLOCK 4
#define BPP (N_NODE / NODES_PER_BLOCK)          // 25000 blocks per pass

// fixed-point scale for weighted-degree accumulation (ea in [0,1), deg < 128)
#define DEG_SCALE 33554432.0f        // 2^25

typedef float  f32x4 __attribute__((ext_vector_type(4)));

__device__ __forceinline__ unsigned int bf16_rne(float f) {
    unsigned int u = __float_as_uint(f);
    return (u + 0x7FFFu + ((u >> 16) & 1u)) >> 16;
}

// ---------------------------------------------------------------------------
// 1. multisplit edges into NB buckets. Per block: LDS histogram -> one global
//    atomic per (block,bucket) reserving a contiguous segment -> segment
//    writes are ~32 edges (256 B) contiguous => ~1.25x line amplification.
__global__ __launch_bounds__(S1_BS) void stage1_bucket(
        const int* __restrict__ ei, const float* __restrict__ ea,
        int* __restrict__ bucket_cursor, int2* __restrict__ bucket) {
    __shared__ int hist[NB];
    __shared__ int segb[NB];
    int tid = threadIdx.x;
    int e0 = blockIdx.x * S1_CHUNK;

    for (int i = tid; i < NB; i += S1_BS) hist[i] = 0;
    __syncthreads();

    for (int k = 0; k < S1_CHUNK; k += S1_BS) {
        int e = e0 + k + tid;
        if (e < N_EDGE) {
            int r = ei[e];
            atomicAdd(&hist[r / RPB], 1);
        }
    }
    __syncthreads();

    for (int i = tid; i < NB; i += S1_BS) {
        int h = hist[i];
        segb[i] = (h > 0) ? atomicAdd(&bucket_cursor[i], h) : 0;
        hist[i] = 0;
    }
    __syncthreads();

    for (int k = 0; k < S1_CHUNK; k += S1_BS) {
        int e = e0 + k + tid;
        if (e < N_EDGE) {
            int r  = ei[e];               // L1-hot (read in pass 1)
            int b  = r / RPB;
            int rl = r - b * RPB;         // < 391, 9 bits
            int c  = ei[N_EDGE + e];      // < 100000, 17 bits
            float w = ea[e];
            int lofs = atomicAdd(&hist[b], 1);
            int pos  = segb[b] + lofs;
            if (pos < CAP)
                bucket[(size_t)b * CAP + pos] =
                    make_int2((rl << 17) | c, __float_as_int(w));
        }
    }
}

// ---------------------------------------------------------------------------
// 2. exclusive scan of NB bucket counts -> CSR bucket bases; a[L]=tanh(alpha)
__global__ void bucket_scan_kernel(const int* __restrict__ bucket_cursor,
                                   int* __restrict__ bucket_base,
                                   const float* __restrict__ alphas,
                                   float* __restrict__ a_vals) {
    __shared__ int sc[NB];
    int tid = threadIdx.x;               // 256 threads
    int v = bucket_cursor[tid];
    sc[tid] = v;
    __syncthreads();
    for (int off = 1; off < NB; off <<= 1) {
        int t = (tid >= off) ? sc[tid - off] : 0;
        __syncthreads();
        sc[tid] += t;
        __syncthreads();
    }
    bucket_base[tid] = sc[tid] - v;      // exclusive
    if (tid < DEPTH + 1) a_vals[tid] = tanhf(alphas[tid]);
}

// ---------------------------------------------------------------------------
// 3. fused per-bucket CSR build: counts + weighted degree (LDS atomics),
//    block scan -> row_ptr/row_end/dinv, then place edges (c, raw w) at exact
//    CSR offsets in a 64KB LDS staging buffer and stream out coalesced.
//    csr keeps RAW w; dinv scaling is folded into the spmm epilogues.
__global__ __launch_bounds__(1024) void stage2_fused(
        const int2* __restrict__ bucket, const int* __restrict__ bucket_cnt,
        const int* __restrict__ bucket_base,
        int* __restrict__ row_ptr, int* __restrict__ row_end,
        float* __restrict__ dinv, int2* __restrict__ csr) {
    __shared__ int          rcnt[RPB];
    __shared__ unsigned int wdeg[RPB];
    __shared__ int          sc[512];
    __shared__ int          lcur[RPB];
    __shared__ int2         staged[CAP];     // 64 KB
    int b = blockIdx.x, tid = threadIdx.x;

    for (int i = tid; i < RPB; i += 1024) { rcnt[i] = 0; wdeg[i] = 0u; }
    __syncthreads();

    int cnt = bucket_cnt[b];
    const int2* src = bucket + (size_t)b * CAP;
    for (int i = tid; i < cnt; i += 1024) {
        int2 e = src[i];
        int rl = e.x >> 17;
        float w = __int_as_float(e.y);
        atomicAdd(&rcnt[rl], 1);
        atomicAdd(&wdeg[rl], (unsigned int)(w * DEG_SCALE + 0.5f));
    }
    __syncthreads();

    // inclusive scan over 512 (RPB padded); all threads hit the barriers
    int v = 0;
    if (tid < 512) { v = (tid < RPB) ? rcnt[tid] : 0; sc[tid] = v; }
    __syncthreads();
    for (int off = 1; off < 512; off <<= 1) {
        int t = 0;
        if (tid < 512 && tid >= off) t = sc[tid - off];
        __syncthreads();
        if (tid < 512) sc[tid] += t;
        __syncthreads();
    }

    int base_b = bucket_base[b];
    if (tid < RPB) {
        int excl = sc[tid] - v;
        lcur[tid] = excl;
        int row = b * RPB + tid;
        if (row < N_NODE) {
            row_ptr[row] = base_b + excl;
            row_end[row] = base_b + excl + rcnt[tid];
            float d = (float)wdeg[tid] * (1.0f / DEG_SCALE);
            dinv[row] = (d > 0.0f) ? rsqrtf(d) : 0.0f;
        }
    }
    __syncthreads();

    for (int i = tid; i < cnt; i += 1024) {
        int2 e = src[i];                   // second read: L2-hot 64KB slice
        int rl = e.x >> 17;
        int c  = e.x & 0x1FFFF;
        int pos = atomicAdd(&lcur[rl], 1);
        staged[pos] = make_int2(c, e.y);   // keep raw w
    }
    __syncthreads();

    for (int i = tid; i < cnt; i += 1024) csr[base_b + i] = staged[i];
}

// ---------------------------------------------------------------------------
// 4. out[n,0,d] = x[n,d] (exact, nt store); bf16 shadow hb0 pass-major:
//    hb0[(pass*N + n)*FPP + f] = bf16(dinv[n]*x[n][pass*FPP+f])
__global__ void init_out_kernel(const float* __restrict__ x,
                                const float* __restrict__ dinv,
                                float* __restrict__ out,
                                unsigned short* __restrict__ hb0,
                                int write_hb) {
    int i = blockIdx.x * blockDim.x + threadIdx.x;   // one per 4 feats
    if (i < N_NODE * (D_FEAT / 4)) {
        int n  = i >> 4;
        int d4 = (i & 15) << 2;
        float4 v = *(const float4*)&x[(size_t)n * D_FEAT + d4];
        f32x4 vv = {v.x, v.y, v.z, v.w};
        __builtin_nontemporal_store(
            vv, (f32x4*)&out[(size_t)n * OUT_STRIDE + d4]);
        if (write_hb) {
            float s = dinv[n];
            int pass = d4 >> 4;
            int fo   = d4 & 15;
            uint2 o;
            o.x = bf16_rne(v.x * s) | (bf16_rne(v.y * s) << 16);
            o.y = bf16_rne(v.z * s) | (bf16_rne(v.w * s) << 16);
            *(uint2*)&hb0[((size_t)pass * N_NODE + n) * FPP + fo] = o;
        }
    }
}

// ---------------------------------------------------------------------------
// 5a. feature-split gather SpMM, bf16 dinv-scaled pass-major source.
//     One launch per layer; pass = blockIdx.x / BPP (pass-major dispatch =>
//     the 3.2MB table slice stays L2-resident on every XCD).
//     Per wave: node; 32 edge-subgroups x 2 lanes x 8 feats (uint4 loads).
//     out_L[i] = aL*dinv_i * sum w_e*g[col_e];  g_L[i] = dinv_i*out_L[i]
__global__ __launch_bounds__(256) void spmm_bf16_kernel(
        const int* __restrict__ row_ptr,
        const int* __restrict__ row_end,
        const int2* __restrict__ csr,
        const float* __restrict__ a_vals,
        const float* __restrict__ dinv,
        const unsigned short* __restrict__ hsrc,
        unsigned short* __restrict__ hdst,
        float* __restrict__ out,
        int L, int write_hdst) {
    int pass = blockIdx.x / BPP;
    int nb   = blockIdx.x - pass * BPP;
    int node = nb * NODES_PER_BLOCK + (threadIdx.x >> 6);
    int lane = threadIdx.x & 63;
    int beg = row_ptr[node];
    int end = row_end[node];
    int s = lane >> 1;        // edge subgroup 0..31
    int f = lane & 1;         // feature half (8 feats each)

    const unsigned short* slab = hsrc + (size_t)pass * N_NODE * FPP;

    float acc[8] = {0, 0, 0, 0, 0, 0, 0, 0};

    for (int chunk = beg; chunk < end; chunk += 64) {
        int idx = chunk + lane;
        int2 pv = make_int2(0, 0);
        if (idx < end) {
            long long t =
                __builtin_nontemporal_load((const long long*)(csr + idx));
            pv = *(int2*)&t;
        }
        int navail = end - chunk;
        if (navail > 64) navail = 64;
        for (int t = 0; t < navail; t += 32) {
            int sub = t + s;
            int   cc = __shfl(pv.x, sub);
            float vv = __int_as_float(__shfl(pv.y, sub));
            bool valid = (sub < navail);
            int   c_safe = valid ? cc : 0;
            float v_safe = valid ? vv : 0.0f;
            uint4 hv = *(const uint4*)&slab[(size_t)c_safe * FPP + (f << 3)];
            acc[0] += v_safe * __uint_as_float((hv.x & 0xFFFFu) << 16);
            acc[1] += v_safe * __uint_as_float(hv.x & 0xFFFF0000u);
            acc[2] += v_safe * __uint_as_float((hv.y & 0xFFFFu) << 16);
            acc[3] += v_safe * __uint_as_float(hv.y & 0xFFFF0000u);
            acc[4] += v_safe * __uint_as_float((hv.z & 0xFFFFu) << 16);
            acc[5] += v_safe * __uint_as_float(hv.z & 0xFFFF0000u);
            acc[6] += v_safe * __uint_as_float((hv.w & 0xFFFFu) << 16);
            acc[7] += v_safe * __uint_as_float(hv.w & 0xFFFF0000u);
        }
    }

    // even-offset tree: even lanes (f=0) fold into lane0, odd (f=1) into lane1
    #pragma unroll
    for (int j = 0; j < 8; ++j) {
        acc[j] += __shfl_down(acc[j], 32);
        acc[j] += __shfl_down(acc[j], 16);
        acc[j] += __shfl_down(acc[j], 8);
        acc[j] += __shfl_down(acc[j], 4);
        acc[j] += __shfl_down(acc[j], 2);
    }

    if (lane < 2) {
        float di = dinv[node];
        float aL = a_vals[L];
        float s1 = aL * di;          // out scale
        float s2 = s1 * di;          // next-shadow scale
        f32x4 r0 = {s1 * acc[0], s1 * acc[1], s1 * acc[2], s1 * acc[3]};
        f32x4 r1 = {s1 * acc[4], s1 * acc[5], s1 * acc[6], s1 * acc[7]};
        size_t ob = (size_t)node * OUT_STRIDE + L * D_FEAT + pass * FPP
                  + (lane << 3);
        __builtin_nontemporal_store(r0, (f32x4*)&out[ob]);
        __builtin_nontemporal_store(r1, (f32x4*)&out[ob + 4]);
        if (write_hdst) {
            uint4 o;
            o.x = bf16_rne(s2 * acc[0]) | (bf16_rne(s2 * acc[1]) << 16);
            o.y = bf16_rne(s2 * acc[2]) | (bf16_rne(s2 * acc[3]) << 16);
            o.z = bf16_rne(s2 * acc[4]) | (bf16_rne(s2 * acc[5]) << 16);
            o.w = bf16_rne(s2 * acc[6]) | (bf16_rne(s2 * acc[7]) << 16);
            *(uint4*)&hdst[((size_t)pass * N_NODE + node) * FPP + (lane << 3)] = o;
        }
    }
}

// 5b. fallback fp32-source gather (used only if ws too small for shadows).
//     csr holds raw w -> needs dinv[c] gather + dinv_i epilogue scale.
__global__ void spmm_f32_kernel(const int* __restrict__ row_ptr,
                                const int* __restrict__ row_end,
                                const int2* __restrict__ csr,
                                const float* __restrict__ a_vals,
                                const float* __restrict__ dinv,
                                float* __restrict__ out,
                                int L) {
    int node = blockIdx.x * (blockDim.x >> 6) + (threadIdx.x >> 6);
    int lane = threadIdx.x & 63;
    if (node >= N_NODE) return;
    int beg = row_ptr[node];
    int end = row_end[node];
    int g = lane >> 4;
    int q = lane & 15;
    int src_base = (L - 1) * D_FEAT + (q << 2);

    float4 acc = make_float4(0.0f, 0.0f, 0.0f, 0.0f);
    for (int chunk = beg; chunk < end; chunk += 64) {
        int idx = chunk + lane;
        int2 pv = (idx < end) ? csr[idx] : make_int2(0, 0);
        int navail = end - chunk;
        if (navail > 64) navail = 64;
        for (int t = 0; t < navail; t += 4) {
            int sub = t + g;
            int   cc = __shfl(pv.x, sub);
            float vv = __int_as_float(__shfl(pv.y, sub));
            bool valid = (sub < navail);
            int   c_safe = valid ? cc : 0;
            float v_safe = valid ? (vv * dinv[c_safe]) : 0.0f;
            const float4 hv =
                *(const float4*)&out[(size_t)c_safe * OUT_STRIDE + src_base];
            acc.x += v_safe * hv.x;
            acc.y += v_safe * hv.y;
            acc.z += v_safe * hv.z;
            acc.w += v_safe * hv.w;
        }
    }
    acc.x += __shfl_down(acc.x, 32);
    acc.y += __shfl_down(acc.y, 32);
    acc.z += __shfl_down(acc.z, 32);
    acc.w += __shfl_down(acc.w, 32);
    acc.x += __shfl_down(acc.x, 16);
    acc.y += __shfl_down(acc.y, 16);
    acc.z += __shfl_down(acc.z, 16);
    acc.w += __shfl_down(acc.w, 16);
    if (g == 0) {
        float s1 = a_vals[L] * dinv[node];
        float4 r = make_float4(s1 * acc.x, s1 * acc.y, s1 * acc.z, s1 * acc.w);
        *(float4*)&out[(size_t)node * OUT_STRIDE + L * D_FEAT + (q << 2)] = r;
    }
}

// ---------------------------------------------------------------------------
extern "C" void kernel_launch(void* const* d_in, const int* in_sizes, int n_in,
                              void* d_out, int out_size, void* d_ws, size_t ws_size,
                              hipStream_t stream) {
    const float* x      = (const float*)d_in[0];
    const int*   ei     = (const int*)d_in[1];   // [2, E] int32
    const float* ea     = (const float*)d_in[2];
    const float* alphas = (const float*)d_in[3];
    float*       out    = (float*)d_out;

    // workspace layout (bucket store aliases the bf16 shadows: bucket data is
    // dead before init_out runs)
    int2*  csr          = (int2*)d_ws;                       // E     (12.8 MB)
    int*   row_ptr      = (int*)(csr + N_EDGE);              // N
    int*   row_end      = row_ptr + N_NODE;                  // N
    float* dinv         = (float*)(row_end + N_NODE);        // N
    int*   bucket_cursor= (int*)(dinv + N_NODE);             // NB
    int*   bucket_base  = bucket_cursor + NB;                // NB
    float* a_vals       = (float*)(bucket_base + NB);        // 4
    int2*  bucket       = (int2*)(a_vals + 4);               // NB*CAP (16.8 MB)
    unsigned short* hb0 = (unsigned short*)bucket;           // union w/ bucket
    unsigned short* hb1 = hb0 + (size_t)N_NODE * D_FEAT;

    size_t base_bytes = (size_t)((char*)bucket - (char*)d_ws);
    size_t need_bf16  = base_bytes +
        2 * (size_t)N_NODE * D_FEAT * sizeof(unsigned short);   // ~39.7 MB
    int use_bf16 = (ws_size >= need_bf16) ? 1 : 0;

    hipMemsetAsync(bucket_cursor, 0, NB * sizeof(int), stream);

    stage1_bucket<<<S1_BLOCKS, S1_BS, 0, stream>>>(ei, ea, bucket_cursor, bucket);
    bucket_scan_kernel<<<1, NB, 0, stream>>>(bucket_cursor, bucket_base,
                                             alphas, a_vals);
    stage2_fused<<<NB, 1024, 0, stream>>>(bucket, bucket_cursor, bucket_base,
                                          row_ptr, row_end, dinv, csr);
    init_out_kernel<<<(N_NODE * (D_FEAT / 4) + 255) / 256, 256, 0, stream>>>(
        x, dinv, out, hb0, use_bf16);

    if (use_bf16) {
        // one launch per layer, pass-major grid (PASSES * BPP blocks)
        int grid = PASSES * BPP;
        spmm_bf16_kernel<<<grid, 256, 0, stream>>>(row_ptr, row_end, csr,
            a_vals, dinv, hb0, hb1, out, 1, 1);
        spmm_bf16_kernel<<<grid, 256, 0, stream>>>(row_ptr, row_end, csr,
            a_vals, dinv, hb1, hb0, out, 2, 1);
        spmm_bf16_kernel<<<grid, 256, 0, stream>>>(row_ptr, row_end, csr,
            a_vals, dinv, hb0, hb1, out, 3, 0);
    } else {
        int nodes_per_block = 256 / 64;
        int spmm_blocks = (N_NODE + nodes_per_block - 1) / nodes_per_block;
        for (int L = 1; L <= DEPTH; ++L) {
            spmm_f32_kernel<<<spmm_blocks, 256, 0, stream>>>(row_ptr, row_end, csr,
                a_vals, dinv, out, L);
        }
    }
}

// Round 5
// 331.334 us; speedup vs baseline: 2.1030x; 2.1030x over previous
//
#include <hip/hip_runtime.h>
#include <math.h>

#define N_NODE 100000
#define N_EDGE 1600000
#define D_FEAT 64
#define DEPTH  3
#define OUT_STRIDE ((DEPTH + 1) * D_FEAT)   // 256 floats per node row

// ---- bucketed CSR build ----------------------------------------------------
#define NB  256                      // coarse buckets
#define RPB 391                      // rows per bucket: 256*391 = 100096 >= N
#define CAP 8192                     // per-bucket edge capacity (mean 6250, +24 sigma)
#define S1_BS 512
#define S1_CHUNK 8192                // edges per stage1 block
#define S1_BLOCKS ((N_EDGE + S1_CHUNK - 1) / S1_CHUNK)   // 196

// ---- column-octant grouping (gather locality) ------------------------------
#define NOCT 16
#define OCT_DIV 6250                 // cols per octant slice (16 x 6250 = 100000)
#define NCELL (RPB * NOCT)           // 6256 (row, octant) cells
#define NCHUNK (NCELL / 8)           // 782 scan chunks of 8

// fixed-point scale for weighted-degree accumulation (ea in [0,1), deg < 128)
#define DEG_SCALE 33554432.0f        // 2^25

typedef float  f32x4 __attribute__((ext_vector_type(4)));

__device__ __forceinline__ unsigned int bf16_rne(float f) {
    unsigned int u = __float_as_uint(f);
    return (u + 0x7FFFu + ((u >> 16) & 1u)) >> 16;
}

// ---------------------------------------------------------------------------
// 1. multisplit edges into NB buckets. Per block: LDS histogram -> one global
//    atomic per (block,bucket) reserving a contiguous segment -> segment
//    writes are ~32 edges (256 B) contiguous => ~1.25x line amplification.
__global__ __launch_bounds__(S1_BS) void stage1_bucket(
        const int* __restrict__ ei, const float* __restrict__ ea,
        int* __restrict__ bucket_cursor, int2* __restrict__ bucket) {
    __shared__ int hist[NB];
    __shared__ int segb[NB];
    int tid = threadIdx.x;
    int e0 = blockIdx.x * S1_CHUNK;

    for (int i = tid; i < NB; i += S1_BS) hist[i] = 0;
    __syncthreads();

    for (int k = 0; k < S1_CHUNK; k += S1_BS) {
        int e = e0 + k + tid;
        if (e < N_EDGE) {
            int r = ei[e];
            atomicAdd(&hist[r / RPB], 1);
        }
    }
    __syncthreads();

    for (int i = tid; i < NB; i += S1_BS) {
        int h = hist[i];
        segb[i] = (h > 0) ? atomicAdd(&bucket_cursor[i], h) : 0;
        hist[i] = 0;
    }
    __syncthreads();

    for (int k = 0; k < S1_CHUNK; k += S1_BS) {
        int e = e0 + k + tid;
        if (e < N_EDGE) {
            int r  = ei[e];               // L1-hot (read in pass 1)
            int b  = r / RPB;
            int rl = r - b * RPB;         // < 391, 9 bits
            int c  = ei[N_EDGE + e];      // < 100000, 17 bits
            float w = ea[e];
            int lofs = atomicAdd(&hist[b], 1);
            int pos  = segb[b] + lofs;
            if (pos < CAP)
                bucket[(size_t)b * CAP + pos] =
                    make_int2((rl << 17) | c, __float_as_int(w));
        }
    }
}

// ---------------------------------------------------------------------------
// 2. exclusive scan of NB bucket counts -> CSR bucket bases; a[L]=tanh(alpha)
__global__ void bucket_scan_kernel(const int* __restrict__ bucket_cursor,
                                   int* __restrict__ bucket_base,
                                   const float* __restrict__ alphas,
                                   float* __restrict__ a_vals) {
    __shared__ int sc[NB];
    int tid = threadIdx.x;               // 256 threads
    int v = bucket_cursor[tid];
    sc[tid] = v;
    __syncthreads();
    for (int off = 1; off < NB; off <<= 1) {
        int t = (tid >= off) ? sc[tid - off] : 0;
        __syncthreads();
        sc[tid] += t;
        __syncthreads();
    }
    bucket_base[tid] = sc[tid] - v;      // exclusive
    if (tid < DEPTH + 1) a_vals[tid] = tanhf(alphas[tid]);
}

// ---------------------------------------------------------------------------
// 3. fused per-bucket CSR build with (row, col-octant) grouping:
//    2D histogram + scan in LDS -> exact slot for every edge in ONE placement
//    pass -> per-row edges come out grouped by ascending col-octant, so the
//    spmm's concurrent waves sweep the gather table front-to-back together
//    (L2-residency window ~half table instead of all of it).
//    csr keeps RAW w; dinv scaling is folded into the spmm epilogues.
__global__ __launch_bounds__(1024) void stage2_fused(
        const int2* __restrict__ bucket, const int* __restrict__ bucket_cnt,
        const int* __restrict__ bucket_base,
        int* __restrict__ row_ptr, int* __restrict__ row_end,
        float* __restrict__ dinv, int2* __restrict__ csr) {
    __shared__ int          cnt2[NCELL];     // (row, oct) counts -> offsets -> cursors
    __shared__ unsigned int wdeg[RPB];
    __shared__ int          sc[1024];
    __shared__ int2         staged[CAP];     // 64 KB
    int b = blockIdx.x, tid = threadIdx.x;

    for (int i = tid; i < NCELL; i += 1024) cnt2[i] = 0;
    if (tid < RPB) wdeg[tid] = 0u;
    __syncthreads();

    int cnt = bucket_cnt[b];
    const int2* src = bucket + (size_t)b * CAP;

    // pass 1: 2D histogram + weighted degree
    for (int i = tid; i < cnt; i += 1024) {
        int2 e = src[i];
        int rl = e.x >> 17;
        int c  = e.x & 0x1FFFF;
        int oc = c / OCT_DIV;               // 0..15
        atomicAdd(&cnt2[rl * NOCT + oc], 1);
        atomicAdd(&wdeg[rl],
                  (unsigned int)(__int_as_float(e.y) * DEG_SCALE + 0.5f));
    }
    __syncthreads();

    // exclusive scan over the 6256 cells: chunk-of-8 local sums + Hillis-Steele
    int lsum = 0;
    if (tid < NCHUNK) {
        int base = tid * 8;
        #pragma unroll
        for (int j = 0; j < 8; ++j) lsum += cnt2[base + j];
    }
    sc[tid] = lsum;
    __syncthreads();
    for (int off = 1; off < 1024; off <<= 1) {
        int t = (tid >= off) ? sc[tid - off] : 0;
        __syncthreads();
        sc[tid] += t;
        __syncthreads();
    }
    if (tid < NCHUNK) {
        int run = sc[tid] - lsum;           // exclusive chunk base
        int base = tid * 8;
        #pragma unroll
        for (int j = 0; j < 8; ++j) {
            int v = cnt2[base + j];
            cnt2[base + j] = run;
            run += v;
        }
    }
    __syncthreads();

    // row tables (read cnt2 before placement mutates it)
    int base_b = bucket_base[b];
    if (tid < RPB) {
        int row = b * RPB + tid;
        if (row < N_NODE) {
            int rb = cnt2[tid * NOCT];
            int re = (tid == RPB - 1) ? cnt : cnt2[(tid + 1) * NOCT];
            row_ptr[row] = base_b + rb;
            row_end[row] = base_b + re;
            float d = (float)wdeg[tid] * (1.0f / DEG_SCALE);
            dinv[row] = (d > 0.0f) ? rsqrtf(d) : 0.0f;
        }
    }
    __syncthreads();

    // pass 2: place each edge at its exact (row, octant) slot
    for (int i = tid; i < cnt; i += 1024) {
        int2 e = src[i];
        int rl = e.x >> 17;
        int c  = e.x & 0x1FFFF;
        int oc = c / OCT_DIV;
        int pos = atomicAdd(&cnt2[rl * NOCT + oc], 1);
        staged[pos] = make_int2(c, e.y);    // keep raw w
    }
    __syncthreads();

    for (int i = tid; i < cnt; i += 1024) csr[base_b + i] = staged[i];
}

// ---------------------------------------------------------------------------
// 4. out[n,0,d] = x[n,d] (exact, nt store); bf16 shadow hb0 = bf16(dinv*x)
__global__ void init_out_kernel(const float* __restrict__ x,
                                const float* __restrict__ dinv,
                                float* __restrict__ out,
                                unsigned short* __restrict__ hb0,
                                int write_hb) {
    int i = blockIdx.x * blockDim.x + threadIdx.x;   // one per 4 feats
    if (i < N_NODE * (D_FEAT / 4)) {
        int n  = i >> 4;
        int d4 = (i & 15) << 2;
        float4 v = *(const float4*)&x[(size_t)n * D_FEAT + d4];
        f32x4 vv = {v.x, v.y, v.z, v.w};
        __builtin_nontemporal_store(
            vv, (f32x4*)&out[(size_t)n * OUT_STRIDE + d4]);
        if (write_hb) {
            float s = dinv[n];
            uint2 o;
            o.x = bf16_rne(v.x * s) | (bf16_rne(v.y * s) << 16);
            o.y = bf16_rne(v.z * s) | (bf16_rne(v.w * s) << 16);
            *(uint2*)&hb0[(size_t)n * D_FEAT + d4] = o;
        }
    }
}

// ---------------------------------------------------------------------------
// 5a. gather SpMM, bf16 dinv-scaled source: wave = node;
//     8 edge-subgroups x 8 lanes x 8 feats (uint4 row loads).
//     Edges per row are octant-sorted -> concurrent waves sweep the table.
//     out_L[i] = aL*dinv_i * sum w_e*g[col_e];  g_L[i] = dinv_i*out_L[i]
__global__ __launch_bounds__(256) void spmm_bf16_kernel(
        const int* __restrict__ row_ptr,
        const int* __restrict__ row_end,
        const int2* __restrict__ csr,
        const float* __restrict__ a_vals,
        const float* __restrict__ dinv,
        const unsigned short* __restrict__ hsrc,
        unsigned short* __restrict__ hdst,
        float* __restrict__ out,
        int L, int write_hdst) {
    int node = blockIdx.x * (blockDim.x >> 6) + (threadIdx.x >> 6);
    int lane = threadIdx.x & 63;
    if (node >= N_NODE) return;
    int beg = row_ptr[node];
    int end = row_end[node];
    int g = lane >> 3;        // edge subgroup 0..7
    int q = lane & 7;         // 8-feature slot

    float acc[8] = {0, 0, 0, 0, 0, 0, 0, 0};

    for (int chunk = beg; chunk < end; chunk += 64) {
        int idx = chunk + lane;
        int2 pv = (idx < end) ? csr[idx] : make_int2(0, 0);
        int navail = end - chunk;
        if (navail > 64) navail = 64;
        for (int t = 0; t < navail; t += 8) {
            int sub = t + g;
            int   cc = __shfl(pv.x, sub);
            float vv = __int_as_float(__shfl(pv.y, sub));
            bool valid = (sub < navail);
            int   c_safe = valid ? cc : 0;
            float v_safe = valid ? vv : 0.0f;
            uint4 hv = *(const uint4*)&hsrc[(size_t)c_safe * D_FEAT + (q << 3)];
            acc[0] += v_safe * __uint_as_float((hv.x & 0xFFFFu) << 16);
            acc[1] += v_safe * __uint_as_float(hv.x & 0xFFFF0000u);
            acc[2] += v_safe * __uint_as_float((hv.y & 0xFFFFu) << 16);
            acc[3] += v_safe * __uint_as_float(hv.y & 0xFFFF0000u);
            acc[4] += v_safe * __uint_as_float((hv.z & 0xFFFFu) << 16);
            acc[5] += v_safe * __uint_as_float(hv.z & 0xFFFF0000u);
            acc[6] += v_safe * __uint_as_float((hv.w & 0xFFFFu) << 16);
            acc[7] += v_safe * __uint_as_float(hv.w & 0xFFFF0000u);
        }
    }

    #pragma unroll
    for (int j = 0; j < 8; ++j) {
        acc[j] += __shfl_down(acc[j], 32);
        acc[j] += __shfl_down(acc[j], 16);
        acc[j] += __shfl_down(acc[j], 8);
    }

    if (g == 0) {
        float di = dinv[node];
        float aL = a_vals[L];
        float s1 = aL * di;          // out scale
        float s2 = s1 * di;          // next-shadow scale
        f32x4 r0 = {s1 * acc[0], s1 * acc[1], s1 * acc[2], s1 * acc[3]};
        f32x4 r1 = {s1 * acc[4], s1 * acc[5], s1 * acc[6], s1 * acc[7]};
        size_t ob = (size_t)node * OUT_STRIDE + L * D_FEAT + (q << 3);
        __builtin_nontemporal_store(r0, (f32x4*)&out[ob]);
        __builtin_nontemporal_store(r1, (f32x4*)&out[ob + 4]);
        if (write_hdst) {
            uint4 o;
            o.x = bf16_rne(s2 * acc[0]) | (bf16_rne(s2 * acc[1]) << 16);
            o.y = bf16_rne(s2 * acc[2]) | (bf16_rne(s2 * acc[3]) << 16);
            o.z = bf16_rne(s2 * acc[4]) | (bf16_rne(s2 * acc[5]) << 16);
            o.w = bf16_rne(s2 * acc[6]) | (bf16_rne(s2 * acc[7]) << 16);
            *(uint4*)&hdst[(size_t)node * D_FEAT + (q << 3)] = o;
        }
    }
}

// 5b. fallback fp32-source gather (used only if ws too small for shadows).
//     csr holds raw w -> needs dinv[c] gather + dinv_i epilogue scale.
__global__ void spmm_f32_kernel(const int* __restrict__ row_ptr,
                                const int* __restrict__ row_end,
                                const int2* __restrict__ csr,
                                const float* __restrict__ a_vals,
                                const float* __restrict__ dinv,
                                float* __restrict__ out,
                                int L) {
    int node = blockIdx.x * (blockDim.x >> 6) + (threadIdx.x >> 6);
    int lane = threadIdx.x & 63;
    if (node >= N_NODE) return;
    int beg = row_ptr[node];
    int end = row_end[node];
    int g = lane >> 4;
    int q = lane & 15;
    int src_base = (L - 1) * D_FEAT + (q << 2);

    float4 acc = make_float4(0.0f, 0.0f, 0.0f, 0.0f);
    for (int chunk = beg; chunk < end; chunk += 64) {
        int idx = chunk + lane;
        int2 pv = (idx < end) ? csr[idx] : make_int2(0, 0);
        int navail = end - chunk;
        if (navail > 64) navail = 64;
        for (int t = 0; t < navail; t += 4) {
            int sub = t + g;
            int   cc = __shfl(pv.x, sub);
            float vv = __int_as_float(__shfl(pv.y, sub));
            bool valid = (sub < navail);
            int   c_safe = valid ? cc : 0;
            float v_safe = valid ? (vv * dinv[c_safe]) : 0.0f;
            const float4 hv =
                *(const float4*)&out[(size_t)c_safe * OUT_STRIDE + src_base];
            acc.x += v_safe * hv.x;
            acc.y += v_safe * hv.y;
            acc.z += v_safe * hv.z;
            acc.w += v_safe * hv.w;
        }
    }
    acc.x += __shfl_down(acc.x, 32);
    acc.y += __shfl_down(acc.y, 32);
    acc.z += __shfl_down(acc.z, 32);
    acc.w += __shfl_down(acc.w, 32);
    acc.x += __shfl_down(acc.x, 16);
    acc.y += __shfl_down(acc.y, 16);
    acc.z += __shfl_down(acc.z, 16);
    acc.w += __shfl_down(acc.w, 16);
    if (g == 0) {
        float s1 = a_vals[L] * dinv[node];
        float4 r = make_float4(s1 * acc.x, s1 * acc.y, s1 * acc.z, s1 * acc.w);
        *(float4*)&out[(size_t)node * OUT_STRIDE + L * D_FEAT + (q << 2)] = r;
    }
}

// ---------------------------------------------------------------------------
extern "C" void kernel_launch(void* const* d_in, const int* in_sizes, int n_in,
                              void* d_out, int out_size, void* d_ws, size_t ws_size,
                              hipStream_t stream) {
    const float* x      = (const float*)d_in[0];
    const int*   ei     = (const int*)d_in[1];   // [2, E] int32
    const float* ea     = (const float*)d_in[2];
    const float* alphas = (const float*)d_in[3];
    float*       out    = (float*)d_out;

    // workspace layout (bucket store aliases the bf16 shadows: bucket data is
    // dead before init_out runs)
    int2*  csr          = (int2*)d_ws;                       // E     (12.8 MB)
    int*   row_ptr      = (int*)(csr + N_EDGE);              // N
    int*   row_end      = row_ptr + N_NODE;                  // N
    float* dinv         = (float*)(row_end + N_NODE);        // N
    int*   bucket_cursor= (int*)(dinv + N_NODE);             // NB
    int*   bucket_base  = bucket_cursor + NB;                // NB
    float* a_vals       = (float*)(bucket_base + NB);        // 4
    int2*  bucket       = (int2*)(a_vals + 4);               // NB*CAP (16.8 MB)
    unsigned short* hb0 = (unsigned short*)bucket;           // union w/ bucket
    unsigned short* hb1 = hb0 + (size_t)N_NODE * D_FEAT;

    size_t base_bytes = (size_t)((char*)bucket - (char*)d_ws);
    size_t need_bf16  = base_bytes +
        2 * (size_t)N_NODE * D_FEAT * sizeof(unsigned short);   // ~39.7 MB
    int use_bf16 = (ws_size >= need_bf16) ? 1 : 0;

    hipMemsetAsync(bucket_cursor, 0, NB * sizeof(int), stream);

    stage1_bucket<<<S1_BLOCKS, S1_BS, 0, stream>>>(ei, ea, bucket_cursor, bucket);
    bucket_scan_kernel<<<1, NB, 0, stream>>>(bucket_cursor, bucket_base,
                                             alphas, a_vals);
    stage2_fused<<<NB, 1024, 0, stream>>>(bucket, bucket_cursor, bucket_base,
                                          row_ptr, row_end, dinv, csr);
    init_out_kernel<<<(N_NODE * (D_FEAT / 4) + 255) / 256, 256, 0, stream>>>(
        x, dinv, out, hb0, use_bf16);

    int nodes_per_block = 256 / 64;
    int spmm_blocks = (N_NODE + nodes_per_block - 1) / nodes_per_block;
    if (use_bf16) {
        // L=1: src hb0 -> dst hb1 ; L=2: src hb1 -> dst hb0 ; L=3: src hb0, no dst
        spmm_bf16_kernel<<<spmm_blocks, 256, 0, stream>>>(row_ptr, row_end, csr,
            a_vals, dinv, hb0, hb1, out, 1, 1);
        spmm_bf16_kernel<<<spmm_blocks, 256, 0, stream>>>(row_ptr, row_end, csr,
            a_vals, dinv, hb1, hb0, out, 2, 1);
        spmm_bf16_kernel<<<spmm_blocks, 256, 0, stream>>>(row_ptr, row_end, csr,
            a_vals, dinv, hb0, hb1, out, 3, 0);
    } else {
        for (int L = 1; L <= DEPTH; ++L) {
            spmm_f32_kernel<<<spmm_blocks, 256, 0, stream>>>(row_ptr, row_end, csr,
                a_vals, dinv, out, L);
        }
    }
}